// Round 8
// baseline (279.232 us; speedup 1.0000x reference)
//
#include <hip/hip_runtime.h>

#define N_NODES 100000
#define DIM 128
#define NBIN 391     // node bins of 256: bin = r >> 8
#define BINSZ 256
#define NFILL 512    // fill blocks; chunk = E/512 = 3125
#define FCAP 32      // per-(block,bin) slots; mean 8, P(Poisson8>32)*cells ~ 2e-5
#define ENTCAP 4608  // per-bin CSR capacity; mean 4082, +8 sigma
#define SPCAP 4096   // global spill capacity (never used in practice)

typedef __attribute__((ext_vector_type(8))) short bf16x8;
typedef __attribute__((ext_vector_type(4))) float f32x4;

__device__ __forceinline__ unsigned short f2bf(float f) {
  unsigned u = __builtin_bit_cast(unsigned, f);
  u += 0x7fff + ((u >> 16) & 1);  // RNE
  return (unsigned short)(u >> 16);
}
__device__ __forceinline__ float bfhi(unsigned u) {
  return __builtin_bit_cast(float, u & 0xffff0000u);
}
__device__ __forceinline__ float bflo(unsigned u) {
  return __builtin_bit_cast(float, u << 16);
}

// ---------------------------------------------------------------------------
// Kernel 0: convert W1||W2 (fp32, 256x128) to bf16 Wb once; zero spill_cnt.
// ---------------------------------------------------------------------------
__global__ __launch_bounds__(256) void wconv_kernel(
    const float* __restrict__ W1, const float* __restrict__ W2,
    unsigned short* __restrict__ Wb, int* __restrict__ spill_cnt) {
  if (blockIdx.x == 0 && threadIdx.x == 0) *spill_cnt = 0;
  const int v = blockIdx.x * 256 + threadIdx.x;  // 8192 float4s
  const int j = v >> 5, q = v & 31;
  const float* Wrow =
      (j < 128) ? (W1 + (size_t)j * DIM) : (W2 + (size_t)(j - 128) * DIM);
  const float4 val = *(const float4*)(Wrow + 4 * q);
  unsigned short* d = Wb + (size_t)j * DIM + 4 * q;
  const unsigned lo = (unsigned)f2bf(val.x) | ((unsigned)f2bf(val.y) << 16);
  const unsigned hi = (unsigned)f2bf(val.z) | ((unsigned)f2bf(val.w) << 16);
  *(uint2*)d = make_uint2(lo, hi);
}

// ---------------------------------------------------------------------------
// Kernel 1: dual GEMM via bf16 MFMA.  self = x@W1^T -> out (f32, direct
// 64B-segment stores), neigh = x@W2^T -> ws (bf16, LDS-staged coalesced).
// ---------------------------------------------------------------------------
__global__ __launch_bounds__(256, 2) void gemm_kernel(
    const float* __restrict__ x, const unsigned short* __restrict__ Wb,
    float* __restrict__ out, unsigned short* __restrict__ neigh) {
  __shared__ unsigned short xs[128 * 136];  // 34 KB

  const int tid = threadIdx.x;
  const int lane = tid & 63;
  const int w = tid >> 6;
  const int nb = blockIdx.x * 128;
  const int quad = lane >> 4;
  const int l15 = lane & 15;

  // B frags straight from Wb: j = 64w + 16nt + l15, k = 32ks + 8quad + t
  bf16x8 bfrag[4][4];
#pragma unroll
  for (int nt = 0; nt < 4; ++nt) {
    const int j = w * 64 + nt * 16 + l15;
#pragma unroll
    for (int ks = 0; ks < 4; ++ks)
      bfrag[nt][ks] =
          *(const bf16x8*)(Wb + (size_t)j * DIM + ks * 32 + quad * 8);
  }

  // stage A: fp32 -> bf16 packed 8B LDS stores, row stride 136
#pragma unroll
  for (int it = 0; it < 16; ++it) {
    const int v = tid + it * 256;
    const int m = v >> 5, q = v & 31;
    float4 val = make_float4(0.f, 0.f, 0.f, 0.f);
    if (nb + m < N_NODES)
      val = *(const float4*)(x + (size_t)(nb + m) * DIM + 4 * q);
    const unsigned lo = (unsigned)f2bf(val.x) | ((unsigned)f2bf(val.y) << 16);
    const unsigned hi = (unsigned)f2bf(val.z) | ((unsigned)f2bf(val.w) << 16);
    *(uint2*)&xs[m * 136 + 4 * q] = make_uint2(lo, hi);
  }
  __syncthreads();

  f32x4 acc[8][4];
#pragma unroll
  for (int mt = 0; mt < 8; ++mt)
#pragma unroll
    for (int nt = 0; nt < 4; ++nt) acc[mt][nt] = (f32x4){0.f, 0.f, 0.f, 0.f};

#pragma unroll
  for (int ks = 0; ks < 4; ++ks) {
#pragma unroll
    for (int mt = 0; mt < 8; ++mt) {
      const bf16x8 afrag =
          *(const bf16x8*)&xs[(mt * 16 + l15) * 136 + ks * 32 + quad * 8];
#pragma unroll
      for (int nt = 0; nt < 4; ++nt)
        acc[mt][nt] = __builtin_amdgcn_mfma_f32_16x16x32_bf16(
            afrag, bfrag[nt][ks], acc[mt][nt], 0, 0, 0);
    }
  }

  // self epilogue (waves 0,1): direct f32 stores; each wave-instr covers
  // 4 distinct 64B segments (16 lanes x 4B contiguous) -> full lines.
  if (w < 2) {
#pragma unroll
    for (int mt = 0; mt < 8; ++mt)
#pragma unroll
      for (int nt = 0; nt < 4; ++nt) {
        const int col = w * 64 + nt * 16 + l15;
#pragma unroll
        for (int r = 0; r < 4; ++r) {
          const int node = nb + mt * 16 + quad * 4 + r;
          if (node < N_NODES) out[(size_t)node * DIM + col] = acc[mt][nt][r];
        }
      }
  }

  // neigh epilogue (waves 2,3): stage bf16 tile in xs, flush coalesced x4.
  __syncthreads();
  if (w >= 2) {
#pragma unroll
    for (int mt = 0; mt < 8; ++mt)
#pragma unroll
      for (int nt = 0; nt < 4; ++nt) {
        const int col = (w & 1) * 64 + nt * 16 + l15;
#pragma unroll
        for (int r = 0; r < 4; ++r)
          xs[(mt * 16 + quad * 4 + r) * 136 + col] = f2bf(acc[mt][nt][r]);
      }
  }
  __syncthreads();
#pragma unroll
  for (int it = 0; it < 8; ++it) {
    const int v = it * 256 + tid;
    const int row = v >> 4, q = v & 15;  // 16 x 16B chunks per 256B row
    if (nb + row < N_NODES)
      *(uint4*)(neigh + (size_t)(nb + row) * DIM + 8 * q) =
          *(const uint4*)&xs[row * 136 + 8 * q];
  }
}

// ---------------------------------------------------------------------------
// Kernel 2: LDS-staged binning (bin = r>>8), wave-coalesced flush.
// ---------------------------------------------------------------------------
__global__ __launch_bounds__(256, 2) void fill_kernel(
    const int* __restrict__ rows, const int* __restrict__ cols,
    int* __restrict__ counts, unsigned* __restrict__ binned,
    int* __restrict__ spill_cnt, int2* __restrict__ spill, int n_edges) {
  __shared__ unsigned buf[NBIN * FCAP];  // 50 KB
  __shared__ int lcnt[NBIN];
  const int tid = threadIdx.x;
  for (int i = tid; i < NBIN; i += 256) lcnt[i] = 0;
  __syncthreads();

  const int chunk = (n_edges + NFILL - 1) / NFILL;
  const int e0 = blockIdx.x * chunk;
  const int e1 = min(e0 + chunk, n_edges);
  for (int e = e0 + tid; e < e1; e += 256) {
    const int r = rows[e];
    const int c = cols[e];
    const int b = r >> 8;
    const unsigned payload = ((unsigned)(r & 255) << 17) | (unsigned)c;
    const int slot = atomicAdd(&lcnt[b], 1);
    if (slot < FCAP) {
      buf[b * FCAP + slot] = payload;
    } else {  // ~never
      const int sp = atomicAdd(spill_cnt, 1);
      if (sp < SPCAP) spill[sp] = make_int2(r, c);
    }
  }
  __syncthreads();

  const int w = tid >> 6, l = tid & 63;
  for (int b = w; b < NBIN; b += 4) {
    const int cnt = min(lcnt[b], FCAP);
    unsigned* dst = binned + ((size_t)b * NFILL + blockIdx.x) * FCAP;
    for (int i = l; i < cnt; i += 64) dst[i] = buf[b * FCAP + i];
    if (l == 0) counts[b * NFILL + blockIdx.x] = cnt;
  }
}

// ---------------------------------------------------------------------------
// Kernel 3: per-bin counting sort -> exact CSR.  All global traffic
// coalesced: full-row lane-linear compaction read, LDS permute, linear
// flush.  ZERO scattered global stores (R7 lesson).
// ---------------------------------------------------------------------------
__global__ __launch_bounds__(256) void sort_kernel(
    const int* __restrict__ counts, const unsigned* __restrict__ binned,
    int* __restrict__ csr_cols, int* __restrict__ row_ptr,
    int* __restrict__ degs, int* __restrict__ spill_cnt,
    int2* __restrict__ spill) {
  __shared__ int segc[NFILL];       // 2 KB
  __shared__ int ssa[NFILL];        // 2 KB
  __shared__ int ssb[NFILL];        // 2 KB
  __shared__ unsigned entbuf[ENTCAP];  // 18.4 KB
  __shared__ int outbuf[ENTCAP];       // 18.4 KB
  __shared__ int hist[BINSZ], hsa[BINSZ], hsb[BINSZ], cur[BINSZ];  // 4 KB

  const int tid = threadIdx.x;
  const int bin = blockIdx.x;

  // segment counts + inclusive scan over NFILL=512 (ping-pong, 256 thr)
  for (int i = tid; i < NFILL; i += 256) {
    const int c = counts[bin * NFILL + i];
    segc[i] = c;
    ssa[i] = c;
  }
  __syncthreads();
  for (int off = 1; off < NFILL; off <<= 1) {
    for (int i = tid; i < NFILL; i += 256)
      ssb[i] = ssa[i] + ((i >= off) ? ssa[i - off] : 0);
    __syncthreads();
    for (int i = tid; i < NFILL; i += 256) ssa[i] = ssb[i];
    __syncthreads();
  }

  // compaction: read the bin's whole binned row lane-linearly (coalesced)
  const unsigned* brow = binned + (size_t)bin * NFILL * FCAP;
  for (int i = tid; i < NFILL * FCAP; i += 256) {
    const int blk = i >> 5;   // /FCAP
    const int slot = i & 31;  // %FCAP
    const int cnt = segc[blk];
    if (slot < cnt) {
      const int pos = ssa[blk] - cnt + slot;
      const unsigned p = brow[i];
      if (pos < ENTCAP) {
        entbuf[pos] = p;
      } else {  // ~never
        const int sp = atomicAdd(spill_cnt, 1);
        if (sp < SPCAP)
          spill[sp] =
              make_int2((bin << 8) | (int)(p >> 17), (int)(p & 0x1FFFFu));
      }
    }
  }
  if (tid < BINSZ) hist[tid] = 0;
  __syncthreads();

  const int total = min(ssa[NFILL - 1], ENTCAP);
  for (int i = tid; i < total; i += 256)
    atomicAdd(&hist[entbuf[i] >> 17], 1);
  __syncthreads();

  // 256-wide inclusive scan of hist
  hsa[tid] = hist[tid];
  __syncthreads();
  for (int off = 1; off < BINSZ; off <<= 1) {
    hsb[tid] = hsa[tid] + ((tid >= off) ? hsa[tid - off] : 0);
    __syncthreads();
    hsa[tid] = hsb[tid];
    __syncthreads();
  }

  const int gbase = bin * ENTCAP;
  {
    const int start = hsa[tid] - hist[tid];  // exclusive
    cur[tid] = start;
    const int node = (bin << 8) | tid;
    if (node < N_NODES) {
      row_ptr[node] = gbase + start;
      degs[node] = hist[tid];
    }
  }
  __syncthreads();

  // permute in LDS (atomics + LDS scatter only)
  for (int i = tid; i < total; i += 256) {
    const unsigned p = entbuf[i];
    const int pos = atomicAdd(&cur[p >> 17], 1);
    outbuf[pos] = (int)(p & 0x1FFFFu);
  }
  __syncthreads();

  // linear coalesced flush
  for (int i = tid; i < total; i += 256) csr_cols[gbase + i] = outbuf[i];
}

// ---------------------------------------------------------------------------
// Kernel 4: persistent wave-per-node gather (bf16) + self(RMW on out) + ReLU.
// ---------------------------------------------------------------------------
__global__ __launch_bounds__(256) void agg_kernel(
    const int* __restrict__ row_ptr, const int* __restrict__ degs,
    const int* __restrict__ csr_cols, const unsigned short* __restrict__ neigh,
    const int* __restrict__ spill_cnt, const int2* __restrict__ spill,
    float* __restrict__ out) {
  const int l = threadIdx.x & 63;
  const int wid = blockIdx.x * 4 + (threadIdx.x >> 6);
  const int stride = gridDim.x * 4;
  const unsigned* ng = (const unsigned*)neigh;
  const int sc = min(*spill_cnt, SPCAP);

  for (int node = wid; node < N_NODES; node += stride) {
    const int deg = degs[node];
    const int* cl = csr_cols + row_ptr[node];
    const float2 s = *(const float2*)(out + (size_t)node * DIM + 2 * l);

    float ax = 0.f, ay = 0.f;
    int d = 0;
    for (; d + 8 <= deg; d += 8) {
      unsigned uv[8];
#pragma unroll
      for (int k = 0; k < 8; ++k) uv[k] = ng[(size_t)cl[d + k] * 64 + l];
#pragma unroll
      for (int k = 0; k < 8; ++k) {
        ax += bflo(uv[k]);
        ay += bfhi(uv[k]);
      }
    }
    const int rem = deg - d;
    if (rem) {
      unsigned uv[8];
      const int cdup = cl[d];  // dup row stays in-cache
#pragma unroll
      for (int k = 0; k < 8; ++k) {
        const int ci = (k < rem) ? cl[d + k] : cdup;
        uv[k] = ng[(size_t)ci * 64 + l];
      }
#pragma unroll
      for (int k = 0; k < 8; ++k) {
        if (k < rem) {  // wave-uniform mask
          ax += bflo(uv[k]);
          ay += bfhi(uv[k]);
        }
      }
    }

    for (int i = 0; i < sc; ++i) {  // ~never non-empty
      const int2 e = spill[i];
      if (e.x == node) {
        const unsigned u = ng[(size_t)e.y * 64 + l];
        ax += bflo(u);
        ay += bfhi(u);
      }
    }

    float2 o;
    o.x = fmaxf(s.x + ax, 0.f);
    o.y = fmaxf(s.y + ay, 0.f);
    *(float2*)(out + (size_t)node * DIM + 2 * l) = o;
  }
}

extern "C" void kernel_launch(void* const* d_in, const int* in_sizes, int n_in,
                              void* d_out, int out_size, void* d_ws,
                              size_t ws_size, hipStream_t stream) {
  const float* x = (const float*)d_in[0];
  const int* edge_index = (const int*)d_in[1];  // (2,E): [0]=row(dst), [1]=col(src)
  const float* W1 = (const float*)d_in[2];
  const float* W2 = (const float*)d_in[3];
  float* out = (float*)d_out;

  const int n_edges = in_sizes[1] / 2;
  const int* rows = edge_index;
  const int* cols = edge_index + n_edges;

  // ws layout (~60 MB): neigh 25.6 | binned 25.6 | counts 0.8 | csr 7.2 |
  // row_ptr 0.4 | degs 0.4 | spill_cnt | spill 32K | Wb 64K
  char* p = (char*)d_ws;
  unsigned short* neigh = (unsigned short*)p;
  p += (size_t)N_NODES * DIM * 2;
  unsigned* binned = (unsigned*)p;
  p += (size_t)NBIN * NFILL * FCAP * 4;
  int* counts = (int*)p;
  p += (size_t)NBIN * NFILL * 4;
  int* csr_cols = (int*)p;
  p += (size_t)NBIN * ENTCAP * 4;
  int* row_ptr = (int*)p;
  p += (size_t)N_NODES * 4;
  int* degs = (int*)p;
  p += (size_t)N_NODES * 4;
  int* spill_cnt = (int*)p;
  p += 16;  // int2 alignment
  int2* spill = (int2*)p;
  p += (size_t)SPCAP * sizeof(int2);
  unsigned short* Wb = (unsigned short*)p;  // 64 KB

  wconv_kernel<<<32, 256, 0, stream>>>(W1, W2, Wb, spill_cnt);
  const int n_tiles = (N_NODES + 127) / 128;  // 782
  gemm_kernel<<<n_tiles, 256, 0, stream>>>(x, Wb, out, neigh);
  fill_kernel<<<NFILL, 256, 0, stream>>>(rows, cols, counts, binned, spill_cnt,
                                         spill, n_edges);
  sort_kernel<<<NBIN, 256, 0, stream>>>(counts, binned, csr_cols, row_ptr,
                                        degs, spill_cnt, spill);
  agg_kernel<<<2048, 256, 0, stream>>>(row_ptr, degs, csr_cols, neigh,
                                       spill_cnt, spill, out);
}

// Round 9
// 277.018 us; speedup vs baseline: 1.0080x; 1.0080x over previous
//
#include <hip/hip_runtime.h>

#define N_NODES 100000
#define DIM 128
#define NBIN 391     // node bins of 256: bin = r >> 8
#define BINSZ 256
#define NFILL 512    // fill chunks; chunk = E/512 = 3125
#define FCAP 32      // per-(chunk,bin) slots; cell mean 8; passed R8 twice
#define ENTCAP 4608  // per-bin CSR capacity; mean 4082, +8 sigma
#define FSPB 256     // fill spill slots per chunk (never used)
#define SSPB 256     // sort spill slots per bin (never used)
#define NGEMM 782    // gemm tiles of 128 nodes

typedef __attribute__((ext_vector_type(8))) short bf16x8;
typedef __attribute__((ext_vector_type(4))) float f32x4;

__device__ __forceinline__ unsigned short f2bf(float f) {
  unsigned u = __builtin_bit_cast(unsigned, f);
  u += 0x7fff + ((u >> 16) & 1);  // RNE
  return (unsigned short)(u >> 16);
}
__device__ __forceinline__ float bfhi(unsigned u) {
  return __builtin_bit_cast(float, u & 0xffff0000u);
}
__device__ __forceinline__ float bflo(unsigned u) {
  return __builtin_bit_cast(float, u << 16);
}

// ---------------------------------------------------------------------------
// Kernel 1: FAT kernel = dual GEMM tiles + LDS-staged fill chunks in one
// dispatch (independent work; 3:2 interleaved block routing so both kinds
// co-reside -> overlap MFMA/LDS phase with fetch/atomic phase; kills two
// dispatch boundaries ~13 us each).
// ---------------------------------------------------------------------------
union FatSh {
  unsigned short xs[128 * 136];  // gemm A-tile / epilogue stage, 34.8 KB
  struct {
    unsigned buf[NBIN * FCAP];  // 50.0 KB
    int lcnt[NBIN];
    int fsc;
  } f;  // fill bins, 51.6 KB
};

__global__ __launch_bounds__(256, 2) void fat_kernel(
    const float* __restrict__ x, const float* __restrict__ W1,
    const float* __restrict__ W2, unsigned short* __restrict__ selfb,
    unsigned short* __restrict__ neigh, const int* __restrict__ rows,
    const int* __restrict__ cols, int* __restrict__ counts,
    unsigned* __restrict__ binned, int* __restrict__ fspillc,
    int2* __restrict__ fspill, int n_edges) {
  __shared__ FatSh sh;
  const int tid = threadIdx.x;
  const int g = blockIdx.x / 5, r5 = blockIdx.x % 5;

  if (r5 < 3) {
    // ---------------- GEMM path: tile t of 128 nodes ----------------
    const int t = g * 3 + r5;
    if (t >= NGEMM) return;
    const int lane = tid & 63;
    const int w = tid >> 6;
    const int nb = t * 128;
    const int quad = lane >> 4;
    const int l15 = lane & 15;

    // B frags: in-register f32->bf16 (W rows L2-hot after first tiles)
    bf16x8 bfrag[4][4];
#pragma unroll
    for (int nt = 0; nt < 4; ++nt) {
      const int j = w * 64 + nt * 16 + l15;
      const float* Wrow =
          (j < 128) ? (W1 + (size_t)j * DIM) : (W2 + (size_t)(j - 128) * DIM);
#pragma unroll
      for (int ks = 0; ks < 4; ++ks) {
        const float* p = Wrow + ks * 32 + quad * 8;
        const float4 lo = *(const float4*)(p);
        const float4 hi = *(const float4*)(p + 4);
        bf16x8 v;
        v[0] = (short)f2bf(lo.x); v[1] = (short)f2bf(lo.y);
        v[2] = (short)f2bf(lo.z); v[3] = (short)f2bf(lo.w);
        v[4] = (short)f2bf(hi.x); v[5] = (short)f2bf(hi.y);
        v[6] = (short)f2bf(hi.z); v[7] = (short)f2bf(hi.w);
        bfrag[nt][ks] = v;
      }
    }

    // stage A: fp32 -> bf16, packed 8B LDS stores, row stride 136
#pragma unroll
    for (int it = 0; it < 16; ++it) {
      const int v = tid + it * 256;
      const int m = v >> 5, q = v & 31;
      float4 val = make_float4(0.f, 0.f, 0.f, 0.f);
      if (nb + m < N_NODES)
        val = *(const float4*)(x + (size_t)(nb + m) * DIM + 4 * q);
      const unsigned lo = (unsigned)f2bf(val.x) | ((unsigned)f2bf(val.y) << 16);
      const unsigned hi = (unsigned)f2bf(val.z) | ((unsigned)f2bf(val.w) << 16);
      *(uint2*)&sh.xs[m * 136 + 4 * q] = make_uint2(lo, hi);
    }
    __syncthreads();

    f32x4 acc[8][4];
#pragma unroll
    for (int mt = 0; mt < 8; ++mt)
#pragma unroll
      for (int nt = 0; nt < 4; ++nt) acc[mt][nt] = (f32x4){0.f, 0.f, 0.f, 0.f};

#pragma unroll
    for (int ks = 0; ks < 4; ++ks) {
#pragma unroll
      for (int mt = 0; mt < 8; ++mt) {
        const bf16x8 afrag =
            *(const bf16x8*)&sh.xs[(mt * 16 + l15) * 136 + ks * 32 + quad * 8];
#pragma unroll
        for (int nt = 0; nt < 4; ++nt)
          acc[mt][nt] = __builtin_amdgcn_mfma_f32_16x16x32_bf16(
              afrag, bfrag[nt][ks], acc[mt][nt], 0, 0, 0);
      }
    }

    // epilogue: half-tiles staged bf16 in xs, flushed coalesced (R7 style)
#pragma unroll
    for (int h = 0; h < 2; ++h) {
      __syncthreads();
      if ((w >> 1) == h) {
#pragma unroll
        for (int mt = 0; mt < 8; ++mt)
#pragma unroll
          for (int nt = 0; nt < 4; ++nt) {
            const int col = (w & 1) * 64 + nt * 16 + l15;
#pragma unroll
            for (int r = 0; r < 4; ++r)
              sh.xs[(mt * 16 + quad * 4 + r) * 136 + col] =
                  f2bf(acc[mt][nt][r]);
          }
      }
      __syncthreads();
      unsigned short* dst = h ? neigh : selfb;
#pragma unroll
      for (int it = 0; it < 8; ++it) {
        const int v = it * 256 + tid;
        const int row = v >> 4, q = v & 15;
        if (nb + row < N_NODES)
          *(uint4*)(dst + (size_t)(nb + row) * DIM + 8 * q) =
              *(const uint4*)&sh.xs[row * 136 + 8 * q];
      }
    }
  } else {
    // ---------------- FILL path: chunk ch of 3125 edges ----------------
    const int ch = g * 2 + (r5 - 3);
    if (ch >= NFILL) return;
    for (int i = tid; i < NBIN; i += 256) sh.f.lcnt[i] = 0;
    if (tid == 0) sh.f.fsc = 0;
    __syncthreads();

    const int chunk = (n_edges + NFILL - 1) / NFILL;
    const int e0 = ch * chunk;
    const int e1 = min(e0 + chunk, n_edges);
    for (int e = e0 + tid; e < e1; e += 256) {
      const int r = rows[e];
      const int c = cols[e];
      const int b = r >> 8;
      const unsigned payload = ((unsigned)(r & 255) << 17) | (unsigned)c;
      const int slot = atomicAdd(&sh.f.lcnt[b], 1);
      if (slot < FCAP) {
        sh.f.buf[b * FCAP + slot] = payload;
      } else {  // ~never: block-private spill, no pre-zeroed global needed
        const int sp = atomicAdd(&sh.f.fsc, 1);
        if (sp < FSPB) fspill[ch * FSPB + sp] = make_int2(r, c);
      }
    }
    __syncthreads();

    const int w = tid >> 6, l = tid & 63;
    for (int b = w; b < NBIN; b += 4) {
      const int cnt = min(sh.f.lcnt[b], FCAP);
      unsigned* dst = binned + ((size_t)b * NFILL + ch) * FCAP;
      for (int i = l; i < cnt; i += 64) dst[i] = sh.f.buf[b * FCAP + i];
      if (l == 0) counts[b * NFILL + ch] = cnt;
    }
    if (tid == 0) fspillc[ch] = min(sh.f.fsc, FSPB);  // ALWAYS written
  }
}

// ---------------------------------------------------------------------------
// Kernel 2: per-bin counting sort -> exact CSR.  Coalesced reads, LDS
// permute, linear flush.  ENTCAP overflow -> bin-private spill (always-
// written count, no pre-zero).
// ---------------------------------------------------------------------------
__global__ __launch_bounds__(256) void sort_kernel(
    const int* __restrict__ counts, const unsigned* __restrict__ binned,
    int* __restrict__ csr_cols, int* __restrict__ row_ptr,
    int* __restrict__ degs, int* __restrict__ sspillc,
    int2* __restrict__ sspill) {
  __shared__ int segc[NFILL];
  __shared__ int ssa[NFILL];
  __shared__ int ssb[NFILL];
  __shared__ unsigned entbuf[ENTCAP];
  __shared__ int outbuf[ENTCAP];
  __shared__ int hist[BINSZ], hsa[BINSZ], hsb[BINSZ], cur[BINSZ];
  __shared__ int ssc;

  const int tid = threadIdx.x;
  const int bin = blockIdx.x;
  if (tid == 0) ssc = 0;

  for (int i = tid; i < NFILL; i += 256) {
    const int c = counts[bin * NFILL + i];
    segc[i] = c;
    ssa[i] = c;
  }
  __syncthreads();
  for (int off = 1; off < NFILL; off <<= 1) {
    for (int i = tid; i < NFILL; i += 256)
      ssb[i] = ssa[i] + ((i >= off) ? ssa[i - off] : 0);
    __syncthreads();
    for (int i = tid; i < NFILL; i += 256) ssa[i] = ssb[i];
    __syncthreads();
  }

  const unsigned* brow = binned + (size_t)bin * NFILL * FCAP;
  for (int i = tid; i < NFILL * FCAP; i += 256) {
    const int blk = i >> 5;
    const int slot = i & 31;
    const int cnt = segc[blk];
    if (slot < cnt) {
      const int pos = ssa[blk] - cnt + slot;
      const unsigned p = brow[i];
      if (pos < ENTCAP) {
        entbuf[pos] = p;
      } else {  // ~never
        const int sp = atomicAdd(&ssc, 1);
        if (sp < SSPB)
          sspill[bin * SSPB + sp] =
              make_int2((bin << 8) | (int)(p >> 17), (int)(p & 0x1FFFFu));
      }
    }
  }
  if (tid < BINSZ) hist[tid] = 0;
  __syncthreads();

  const int total = min(ssa[NFILL - 1], ENTCAP);
  for (int i = tid; i < total; i += 256) atomicAdd(&hist[entbuf[i] >> 17], 1);
  __syncthreads();

  hsa[tid] = hist[tid];
  __syncthreads();
  for (int off = 1; off < BINSZ; off <<= 1) {
    hsb[tid] = hsa[tid] + ((tid >= off) ? hsa[tid - off] : 0);
    __syncthreads();
    hsa[tid] = hsb[tid];
    __syncthreads();
  }

  const int gbase = bin * ENTCAP;
  {
    const int start = hsa[tid] - hist[tid];
    cur[tid] = start;
    const int node = (bin << 8) | tid;
    if (node < N_NODES) {
      row_ptr[node] = gbase + start;
      degs[node] = hist[tid];
    }
  }
  __syncthreads();

  for (int i = tid; i < total; i += 256) {
    const unsigned p = entbuf[i];
    const int pos = atomicAdd(&cur[p >> 17], 1);
    outbuf[pos] = (int)(p & 0x1FFFFu);
  }
  __syncthreads();

  for (int i = tid; i < total; i += 256) csr_cols[gbase + i] = outbuf[i];
  if (tid == 0) sspillc[bin] = min(ssc, SSPB);  // ALWAYS written
}

// ---------------------------------------------------------------------------
// Kernel 3: persistent wave-per-node gather (bf16) + self(bf16) + ReLU.
// Block-level spill detection (3.6 KB L2-hot scan); slow merge only in the
// never-case.
// ---------------------------------------------------------------------------
__global__ __launch_bounds__(256) void agg_kernel(
    const int* __restrict__ row_ptr, const int* __restrict__ degs,
    const int* __restrict__ csr_cols, const unsigned short* __restrict__ neigh,
    const unsigned short* __restrict__ selfb, const int* __restrict__ fspillc,
    const int2* __restrict__ fspill, const int* __restrict__ sspillc,
    const int2* __restrict__ sspill, float* __restrict__ out) {
  __shared__ int has_spill;
  const int tid = threadIdx.x;
  if (tid == 0) has_spill = 0;
  __syncthreads();
  for (int i = tid; i < NFILL + NBIN; i += 256) {
    const int v = (i < NFILL) ? fspillc[i] : sspillc[i - NFILL];
    if (v) atomicOr(&has_spill, 1);
  }
  __syncthreads();
  const bool spilled = has_spill != 0;

  const int l = tid & 63;
  const int wid = blockIdx.x * 4 + (tid >> 6);
  const int stride = gridDim.x * 4;
  const unsigned* ng = (const unsigned*)neigh;

  for (int node = wid; node < N_NODES; node += stride) {
    const int deg = degs[node];
    const int* cl = csr_cols + row_ptr[node];
    const unsigned s = ((const unsigned*)selfb)[(size_t)node * 64 + l];

    float ax = 0.f, ay = 0.f;
    int d = 0;
    for (; d + 8 <= deg; d += 8) {
      unsigned uv[8];
#pragma unroll
      for (int k = 0; k < 8; ++k) uv[k] = ng[(size_t)cl[d + k] * 64 + l];
#pragma unroll
      for (int k = 0; k < 8; ++k) {
        ax += bflo(uv[k]);
        ay += bfhi(uv[k]);
      }
    }
    const int rem = deg - d;
    if (rem) {
      unsigned uv[8];
      const int cdup = cl[d];  // dup row stays in-cache
#pragma unroll
      for (int k = 0; k < 8; ++k) {
        const int ci = (k < rem) ? cl[d + k] : cdup;
        uv[k] = ng[(size_t)ci * 64 + l];
      }
#pragma unroll
      for (int k = 0; k < 8; ++k) {
        if (k < rem) {  // wave-uniform mask
          ax += bflo(uv[k]);
          ay += bfhi(uv[k]);
        }
      }
    }

    if (spilled) {  // never taken in practice
      for (int bi = 0; bi < NFILL; ++bi) {
        const int n = min(fspillc[bi], FSPB);
        for (int i = 0; i < n; ++i) {
          const int2 e = fspill[bi * FSPB + i];
          if (e.x == node) {
            const unsigned u = ng[(size_t)e.y * 64 + l];
            ax += bflo(u);
            ay += bfhi(u);
          }
        }
      }
      for (int bi = 0; bi < NBIN; ++bi) {
        const int n = min(sspillc[bi], SSPB);
        for (int i = 0; i < n; ++i) {
          const int2 e = sspill[bi * SSPB + i];
          if (e.x == node) {
            const unsigned u = ng[(size_t)e.y * 64 + l];
            ax += bflo(u);
            ay += bfhi(u);
          }
        }
      }
    }

    float2 o;
    o.x = fmaxf(bflo(s) + ax, 0.f);
    o.y = fmaxf(bfhi(s) + ay, 0.f);
    *(float2*)(out + (size_t)node * DIM + 2 * l) = o;
  }
}

extern "C" void kernel_launch(void* const* d_in, const int* in_sizes, int n_in,
                              void* d_out, int out_size, void* d_ws,
                              size_t ws_size, hipStream_t stream) {
  const float* x = (const float*)d_in[0];
  const int* edge_index = (const int*)d_in[1];  // (2,E): [0]=row(dst), [1]=col(src)
  const float* W1 = (const float*)d_in[2];
  const float* W2 = (const float*)d_in[3];
  float* out = (float*)d_out;

  const int n_edges = in_sizes[1] / 2;
  const int* rows = edge_index;
  const int* cols = edge_index + n_edges;

  // ws layout (~87 MB): selfb 25.6 | neigh 25.6 | binned 25.6 | counts 0.8 |
  // csr 7.2 | row_ptr 0.4 | degs 0.4 | fspillc 2K | fspill 1M |
  // sspillc 2K | sspill 0.8M
  char* p = (char*)d_ws;
  unsigned short* selfb = (unsigned short*)p;
  p += (size_t)N_NODES * DIM * 2;
  unsigned short* neigh = (unsigned short*)p;
  p += (size_t)N_NODES * DIM * 2;
  unsigned* binned = (unsigned*)p;
  p += (size_t)NBIN * NFILL * FCAP * 4;
  int* counts = (int*)p;
  p += (size_t)NBIN * NFILL * 4;
  int* csr_cols = (int*)p;
  p += (size_t)NBIN * ENTCAP * 4;
  int* row_ptr = (int*)p;
  p += (size_t)N_NODES * 4;
  int* degs = (int*)p;
  p += (size_t)N_NODES * 4;
  int* fspillc = (int*)p;
  p += (size_t)NFILL * 4;
  int2* fspill = (int2*)p;
  p += (size_t)NFILL * FSPB * sizeof(int2);
  int* sspillc = (int*)p;
  p += 2048;  // NBIN*4 padded to keep 16B alignment
  int2* sspill = (int2*)p;

  // groups of 5 blocks: 3 gemm tiles + 2 fill chunks (interleaved residency)
  const int n_groups = (NGEMM + 2) / 3;  // 261 -> covers 782 tiles, 512 chunks
  fat_kernel<<<n_groups * 5, 256, 0, stream>>>(x, W1, W2, selfb, neigh, rows,
                                               cols, counts, binned, fspillc,
                                               fspill, n_edges);
  sort_kernel<<<NBIN, 256, 0, stream>>>(counts, binned, csr_cols, row_ptr,
                                        degs, sspillc, sspill);
  agg_kernel<<<2048, 256, 0, stream>>>(row_ptr, degs, csr_cols, neigh, selfb,
                                       fspillc, fspill, sspillc, sspill, out);
}

// Round 10
// 249.629 us; speedup vs baseline: 1.1186x; 1.1097x over previous
//
#include <hip/hip_runtime.h>

#define N_NODES 100000
#define DIM 128
#define NBIN 391      // dest bins of 256 nodes: bin = r >> 8
#define BINSZ 256
#define NCH 782       // fill chunks of 2048 edges
#define CHUNK 2048
#define FCAP 24       // per-(chunk,bin) slots; cell mean 5.24, P(Po>24)*cells ~ 4e-5
#define SLOTS (NBIN * FCAP)  // 9384 dwords per chunk (ch-major plane)
#define ENTCAP 4608   // per-bin CSR capacity; mean 4092, +8 sigma
#define FSPB 128      // fill spill slots per chunk (never used)
#define SSPB 256      // sort spill slots per bin (never used)

typedef __attribute__((ext_vector_type(8))) short bf16x8;
typedef __attribute__((ext_vector_type(4))) float f32x4;

__device__ __forceinline__ unsigned short f2bf(float f) {
  unsigned u = __builtin_bit_cast(unsigned, f);
  u += 0x7fff + ((u >> 16) & 1);  // RNE
  return (unsigned short)(u >> 16);
}
__device__ __forceinline__ float bfhi(unsigned u) {
  return __builtin_bit_cast(float, u & 0xffff0000u);
}
__device__ __forceinline__ float bflo(unsigned u) {
  return __builtin_bit_cast(float, u << 16);
}

// ---------------------------------------------------------------------------
// Kernel 1: dual GEMM via bf16 MFMA.  A-tile loads issued FIRST (16
// independent float4/thread); W fp32->bf16 conversion VALU hides under them.
// selfb = x@W1^T, neigh = x@W2^T (both bf16, coalesced LDS-staged stores).
// ---------------------------------------------------------------------------
__global__ __launch_bounds__(256, 2) void gemm_kernel(
    const float* __restrict__ x, const float* __restrict__ W1,
    const float* __restrict__ W2, unsigned short* __restrict__ selfb,
    unsigned short* __restrict__ neigh) {
  __shared__ unsigned short xs[128 * 136];  // 34.8 KB

  const int tid = threadIdx.x;
  const int lane = tid & 63;
  const int w = tid >> 6;
  const int nb = blockIdx.x * 128;
  const int quad = lane >> 4;
  const int l15 = lane & 15;

  // 1) issue A-tile loads first (latency overlapped by step 2)
  float4 av[16];
#pragma unroll
  for (int it = 0; it < 16; ++it) {
    const int v = tid + it * 256;
    const int m = v >> 5, q = v & 31;
    av[it] = (nb + m < N_NODES)
                 ? *(const float4*)(x + (size_t)(nb + m) * DIM + 4 * q)
                 : make_float4(0.f, 0.f, 0.f, 0.f);
  }

  // 2) B frags: W loads (L2-hot after first blocks) + f32->bf16 cvt
  bf16x8 bfrag[4][4];
#pragma unroll
  for (int nt = 0; nt < 4; ++nt) {
    const int j = w * 64 + nt * 16 + l15;
    const float* Wrow =
        (j < 128) ? (W1 + (size_t)j * DIM) : (W2 + (size_t)(j - 128) * DIM);
#pragma unroll
    for (int ks = 0; ks < 4; ++ks) {
      const float* p = Wrow + ks * 32 + quad * 8;
      const float4 lo = *(const float4*)(p);
      const float4 hi = *(const float4*)(p + 4);
      bf16x8 v;
      v[0] = (short)f2bf(lo.x); v[1] = (short)f2bf(lo.y);
      v[2] = (short)f2bf(lo.z); v[3] = (short)f2bf(lo.w);
      v[4] = (short)f2bf(hi.x); v[5] = (short)f2bf(hi.y);
      v[6] = (short)f2bf(hi.z); v[7] = (short)f2bf(hi.w);
      bfrag[nt][ks] = v;
    }
  }

  // 3) pack A into LDS (row stride 136 shorts)
#pragma unroll
  for (int it = 0; it < 16; ++it) {
    const int v = tid + it * 256;
    const int m = v >> 5, q = v & 31;
    const unsigned lo =
        (unsigned)f2bf(av[it].x) | ((unsigned)f2bf(av[it].y) << 16);
    const unsigned hi =
        (unsigned)f2bf(av[it].z) | ((unsigned)f2bf(av[it].w) << 16);
    *(uint2*)&xs[m * 136 + 4 * q] = make_uint2(lo, hi);
  }
  __syncthreads();

  f32x4 acc[8][4];
#pragma unroll
  for (int mt = 0; mt < 8; ++mt)
#pragma unroll
    for (int nt = 0; nt < 4; ++nt) acc[mt][nt] = (f32x4){0.f, 0.f, 0.f, 0.f};

#pragma unroll
  for (int ks = 0; ks < 4; ++ks) {
#pragma unroll
    for (int mt = 0; mt < 8; ++mt) {
      const bf16x8 afrag =
          *(const bf16x8*)&xs[(mt * 16 + l15) * 136 + ks * 32 + quad * 8];
#pragma unroll
      for (int nt = 0; nt < 4; ++nt)
        acc[mt][nt] = __builtin_amdgcn_mfma_f32_16x16x32_bf16(
            afrag, bfrag[nt][ks], acc[mt][nt], 0, 0, 0);
    }
  }

  // epilogue: half-tiles staged bf16 in xs, flushed coalesced uint4
#pragma unroll
  for (int h = 0; h < 2; ++h) {
    __syncthreads();
    if ((w >> 1) == h) {
#pragma unroll
      for (int mt = 0; mt < 8; ++mt)
#pragma unroll
        for (int nt = 0; nt < 4; ++nt) {
          const int col = (w & 1) * 64 + nt * 16 + l15;
#pragma unroll
          for (int r = 0; r < 4; ++r)
            xs[(mt * 16 + quad * 4 + r) * 136 + col] = f2bf(acc[mt][nt][r]);
        }
    }
    __syncthreads();
    unsigned short* dst = h ? neigh : selfb;
#pragma unroll
    for (int it = 0; it < 8; ++it) {
      const int v = it * 256 + tid;
      const int row = v >> 4, q = v & 15;
      if (nb + row < N_NODES)
        *(uint4*)(dst + (size_t)(nb + row) * DIM + 8 * q) =
            *(const uint4*)&xs[row * 136 + 8 * q];
    }
  }
}

// ---------------------------------------------------------------------------
// Kernel 2: LDS-staged binning.  int4 edge loads (8 edges per thread-batch),
// chunk-major binned plane -> flush is an UNCONDITIONAL dense uint4 copy
// (perfectly coalesced); counts written contiguously.  39 KB LDS, tiny
// VGPR -> 4 blocks/CU for latency hiding.
// ---------------------------------------------------------------------------
__global__ __launch_bounds__(256, 4) void fill_kernel(
    const int* __restrict__ rows, const int* __restrict__ cols,
    int* __restrict__ counts, unsigned* __restrict__ binned,
    int* __restrict__ fspillc, int2* __restrict__ fspill, int n_edges) {
  __shared__ unsigned buf[SLOTS];  // 37.5 KB, layout b*FCAP + slot
  __shared__ int lcnt[NBIN];
  __shared__ int fsc;
  const int tid = threadIdx.x;
  const int ch = blockIdx.x;
  for (int i = tid; i < NBIN; i += 256) lcnt[i] = 0;
  if (tid == 0) fsc = 0;
  __syncthreads();

  const int e0 = ch * CHUNK + tid * 8;
  int rv[8], cv[8];
  int nval;
  if (e0 + 8 <= n_edges) {
    *(int4*)&rv[0] = *(const int4*)(rows + e0);
    *(int4*)&rv[4] = *(const int4*)(rows + e0 + 4);
    *(int4*)&cv[0] = *(const int4*)(cols + e0);
    *(int4*)&cv[4] = *(const int4*)(cols + e0 + 4);
    nval = 8;
  } else {
    nval = 0;
    for (int k = 0; k < 8; ++k)
      if (e0 + k < n_edges) {
        rv[nval] = rows[e0 + k];
        cv[nval] = cols[e0 + k];
        ++nval;
      }
  }
  for (int k = 0; k < nval; ++k) {
    const int r = rv[k];
    const int b = r >> 8;
    const unsigned payload = ((unsigned)(r & 255) << 17) | (unsigned)cv[k];
    const int slot = atomicAdd(&lcnt[b], 1);
    if (slot < FCAP) {
      buf[b * FCAP + slot] = payload;
    } else {  // ~never
      const int sp = atomicAdd(&fsc, 1);
      if (sp < FSPB) fspill[ch * FSPB + sp] = make_int2(r, cv[k]);
    }
  }
  __syncthreads();

  // dense coalesced flush: global index ch*SLOTS + i  (i = b*FCAP + slot)
  unsigned* dst = binned + (size_t)ch * SLOTS;
  for (int i4 = tid; i4 < SLOTS / 4; i4 += 256)
    *(uint4*)(dst + 4 * i4) = *(const uint4*)&buf[4 * i4];
  for (int b = tid; b < NBIN; b += 256)
    counts[(size_t)ch * NBIN + b] = min(lcnt[b], FCAP);
  if (tid == 0) fspillc[ch] = min(fsc, FSPB);  // ALWAYS written
}

// ---------------------------------------------------------------------------
// Kernel 3: per-bin counting sort -> exact CSR.  Compaction = 19 independent
// unconditional uint4 loads per thread (R9 lesson: no serialized conditional
// scalar loads).  LDS permute, linear flush.
// ---------------------------------------------------------------------------
__global__ __launch_bounds__(256, 3) void sort_kernel(
    const int* __restrict__ counts, const unsigned* __restrict__ binned,
    int* __restrict__ csr_cols, int* __restrict__ row_ptr,
    int* __restrict__ degs, int* __restrict__ sspillc,
    int2* __restrict__ sspill) {
  __shared__ int segc[NCH];            // 3.1 KB
  __shared__ int ssa[NCH], ssb[NCH];   // 6.2 KB
  __shared__ unsigned entbuf[ENTCAP];  // 18.4 KB
  __shared__ int outbuf[ENTCAP];       // 18.4 KB
  __shared__ int hist[BINSZ], hsa[BINSZ], hsb[BINSZ], cur[BINSZ];  // 4 KB
  __shared__ int ssc;

  const int tid = threadIdx.x;
  const int bin = blockIdx.x;
  if (tid == 0) ssc = 0;

  for (int i = tid; i < NCH; i += 256) {
    const int c = counts[(size_t)i * NBIN + bin];  // independent gathers
    segc[i] = c;
    ssa[i] = c;
  }
  __syncthreads();
  for (int off = 1; off < NCH; off <<= 1) {
    for (int i = tid; i < NCH; i += 256)
      ssb[i] = ssa[i] + ((i >= off) ? ssa[i - off] : 0);
    __syncthreads();
    for (int i = tid; i < NCH; i += 256) ssa[i] = ssb[i];
    __syncthreads();
  }

  // compaction: 782 segs x 6 uint4 = 4692 unconditional 16B loads
  const unsigned* bbase = binned + (size_t)bin * FCAP;
  for (int u = tid; u < NCH * (FCAP / 4); u += 256) {
    const int ch = u / 6;
    const int q = u - ch * 6;
    uint4 v4 = *(const uint4*)(bbase + (size_t)ch * SLOTS + 4 * q);
    const int cnt = segc[ch];
    const int base = ssa[ch] - cnt;  // exclusive prefix
    const unsigned vals[4] = {v4.x, v4.y, v4.z, v4.w};
#pragma unroll
    for (int j = 0; j < 4; ++j) {
      const int slot = 4 * q + j;
      if (slot < cnt) {
        const int pos = base + slot;
        if (pos < ENTCAP) {
          entbuf[pos] = vals[j];
        } else {  // ~never
          const int sp = atomicAdd(&ssc, 1);
          if (sp < SSPB)
            sspill[bin * SSPB + sp] = make_int2(
                (bin << 8) | (int)(vals[j] >> 17), (int)(vals[j] & 0x1FFFFu));
        }
      }
    }
  }
  hist[tid] = 0;
  __syncthreads();

  const int total = min(ssa[NCH - 1], ENTCAP);
  for (int i = tid; i < total; i += 256) atomicAdd(&hist[entbuf[i] >> 17], 1);
  __syncthreads();

  hsa[tid] = hist[tid];
  __syncthreads();
  for (int off = 1; off < BINSZ; off <<= 1) {
    hsb[tid] = hsa[tid] + ((tid >= off) ? hsa[tid - off] : 0);
    __syncthreads();
    hsa[tid] = hsb[tid];
    __syncthreads();
  }

  const int gbase = bin * ENTCAP;
  {
    const int start = hsa[tid] - hist[tid];
    cur[tid] = start;
    const int node = (bin << 8) | tid;
    if (node < N_NODES) {
      row_ptr[node] = gbase + start;
      degs[node] = hist[tid];
    }
  }
  __syncthreads();

  for (int i = tid; i < total; i += 256) {
    const unsigned p = entbuf[i];
    const int pos = atomicAdd(&cur[p >> 17], 1);
    outbuf[pos] = (int)(p & 0x1FFFFu);
  }
  __syncthreads();

  for (int i = tid; i < total; i += 256) csr_cols[gbase + i] = outbuf[i];
  if (tid == 0) sspillc[bin] = min(ssc, SSPB);  // ALWAYS written
}

// ---------------------------------------------------------------------------
// Kernel 4: persistent wave-per-node gather (bf16) + self(bf16) + ReLU.
// Unchanged from R9 (measured-good) except spill table sizes.
// ---------------------------------------------------------------------------
__global__ __launch_bounds__(256) void agg_kernel(
    const int* __restrict__ row_ptr, const int* __restrict__ degs,
    const int* __restrict__ csr_cols, const unsigned short* __restrict__ neigh,
    const unsigned short* __restrict__ selfb, const int* __restrict__ fspillc,
    const int2* __restrict__ fspill, const int* __restrict__ sspillc,
    const int2* __restrict__ sspill, float* __restrict__ out) {
  __shared__ int has_spill;
  const int tid = threadIdx.x;
  if (tid == 0) has_spill = 0;
  __syncthreads();
  for (int i = tid; i < NCH + NBIN; i += 256) {
    const int v = (i < NCH) ? fspillc[i] : sspillc[i - NCH];
    if (v) atomicOr(&has_spill, 1);
  }
  __syncthreads();
  const bool spilled = has_spill != 0;

  const int l = tid & 63;
  const int wid = blockIdx.x * 4 + (tid >> 6);
  const int stride = gridDim.x * 4;
  const unsigned* ng = (const unsigned*)neigh;

  for (int node = wid; node < N_NODES; node += stride) {
    const int deg = degs[node];
    const int* cl = csr_cols + row_ptr[node];
    const unsigned s = ((const unsigned*)selfb)[(size_t)node * 64 + l];

    float ax = 0.f, ay = 0.f;
    int d = 0;
    for (; d + 8 <= deg; d += 8) {
      unsigned uv[8];
#pragma unroll
      for (int k = 0; k < 8; ++k) uv[k] = ng[(size_t)cl[d + k] * 64 + l];
#pragma unroll
      for (int k = 0; k < 8; ++k) {
        ax += bflo(uv[k]);
        ay += bfhi(uv[k]);
      }
    }
    const int rem = deg - d;
    if (rem) {
      unsigned uv[8];
      const int cdup = cl[d];  // dup row stays in-cache
#pragma unroll
      for (int k = 0; k < 8; ++k) {
        const int ci = (k < rem) ? cl[d + k] : cdup;
        uv[k] = ng[(size_t)ci * 64 + l];
      }
#pragma unroll
      for (int k = 0; k < 8; ++k) {
        if (k < rem) {  // wave-uniform mask
          ax += bflo(uv[k]);
          ay += bfhi(uv[k]);
        }
      }
    }

    if (spilled) {  // never taken in practice
      for (int bi = 0; bi < NCH; ++bi) {
        const int n = min(fspillc[bi], FSPB);
        for (int i = 0; i < n; ++i) {
          const int2 e = fspill[bi * FSPB + i];
          if (e.x == node) {
            const unsigned u = ng[(size_t)e.y * 64 + l];
            ax += bflo(u);
            ay += bfhi(u);
          }
        }
      }
      for (int bi = 0; bi < NBIN; ++bi) {
        const int n = min(sspillc[bi], SSPB);
        for (int i = 0; i < n; ++i) {
          const int2 e = sspill[bi * SSPB + i];
          if (e.x == node) {
            const unsigned u = ng[(size_t)e.y * 64 + l];
            ax += bflo(u);
            ay += bfhi(u);
          }
        }
      }
    }

    float2 o;
    o.x = fmaxf(bflo(s) + ax, 0.f);
    o.y = fmaxf(bfhi(s) + ay, 0.f);
    *(float2*)(out + (size_t)node * DIM + 2 * l) = o;
  }
}

extern "C" void kernel_launch(void* const* d_in, const int* in_sizes, int n_in,
                              void* d_out, int out_size, void* d_ws,
                              size_t ws_size, hipStream_t stream) {
  const float* x = (const float*)d_in[0];
  const int* edge_index = (const int*)d_in[1];  // (2,E): [0]=row(dst), [1]=col(src)
  const float* W1 = (const float*)d_in[2];
  const float* W2 = (const float*)d_in[3];
  float* out = (float*)d_out;

  const int n_edges = in_sizes[1] / 2;
  const int* rows = edge_index;
  const int* cols = edge_index + n_edges;

  // ws layout (~91 MB): selfb 25.6 | neigh 25.6 | binned 29.4 | counts 1.2 |
  // csr 7.2 | row_ptr 0.4 | degs 0.4 | fspillc 4K | fspill 0.8M |
  // sspillc 4K | sspill 0.8M
  char* p = (char*)d_ws;
  unsigned short* selfb = (unsigned short*)p;
  p += (size_t)N_NODES * DIM * 2;
  unsigned short* neigh = (unsigned short*)p;
  p += (size_t)N_NODES * DIM * 2;
  unsigned* binned = (unsigned*)p;
  p += (size_t)NCH * SLOTS * 4;
  int* counts = (int*)p;
  p += (size_t)NCH * NBIN * 4;
  int* csr_cols = (int*)p;
  p += (size_t)NBIN * ENTCAP * 4;
  int* row_ptr = (int*)p;
  p += (size_t)N_NODES * 4;
  int* degs = (int*)p;
  p += (size_t)N_NODES * 4;
  int* fspillc = (int*)p;
  p += 4096;
  int2* fspill = (int2*)p;
  p += (size_t)NCH * FSPB * sizeof(int2);
  int* sspillc = (int*)p;
  p += 4096;
  int2* sspill = (int2*)p;

  gemm_kernel<<<(N_NODES + 127) / 128, 256, 0, stream>>>(x, W1, W2, selfb,
                                                         neigh);
  fill_kernel<<<NCH, 256, 0, stream>>>(rows, cols, counts, binned, fspillc,
                                       fspill, n_edges);
  sort_kernel<<<NBIN, 256, 0, stream>>>(counts, binned, csr_cols, row_ptr,
                                        degs, sspillc, sspill);
  agg_kernel<<<2048, 256, 0, stream>>>(row_ptr, degs, csr_cols, neigh, selfb,
                                       fspillc, fspill, sspillc, sspill, out);
}